// Round 8
// baseline (635.735 us; speedup 1.0000x reference)
//
#include <hip/hip_runtime.h>
#include <cstdint>
#include <cfloat>

#define NN 100000
#define NE 1600000
#define NBKT 391          // buckets of 256 dst nodes: (NN+255)/256
#define CHUNK 4096
#define NBLK1 391         // ceil(NE/CHUNK)
#define SCAN_N (NBKT * NBLK1)   // 152881
#define CAP3 5120         // max edges per bucket (mean 4096, sigma 64 -> 16 sigma)

typedef float v4f __attribute__((ext_vector_type(4)));

// wave-0 exclusive scan of cnt[0..nelem) -> lst; caller guards threadIdx.x < 64
__device__ __forceinline__ void excl_scan_lds(const int* cnt, int* lst, int nelem, int per_lane) {
    int lane = threadIdx.x & 63;
    int base = lane * per_lane;
    int run = 0;
    int loc[8];
    for (int j = 0; j < per_lane; ++j) {
        int idx = base + j;
        loc[j] = run;
        if (idx < nelem) run += cnt[idx];
    }
    int tot = run;
    for (int off = 1; off < 64; off <<= 1) {
        int t = __shfl_up(tot, off);
        if (lane >= off) tot += t;
    }
    int pre = tot - run;
    for (int j = 0; j < per_lane; ++j) {
        int idx = base + j;
        if (idx < nelem) lst[idx] = pre + loc[j];
    }
}

// ---------------- CSR build: atomic-free bucket sort (R4, unchanged) ----------------
__global__ __launch_bounds__(256) void k_bcount(const int* __restrict__ dst, int* __restrict__ counts) {
    __shared__ int h[NBKT];
    int tid = threadIdx.x, blk = blockIdx.x;
    for (int i = tid; i < NBKT; i += 256) h[i] = 0;
    __syncthreads();
    int e0 = blk * CHUNK, ee = min(e0 + CHUNK, NE);
    for (int i = e0 + tid; i < ee; i += 256) atomicAdd(&h[dst[i] >> 8], 1);
    __syncthreads();
    for (int i = tid; i < NBKT; i += 256) counts[i * NBLK1 + blk] = h[i];
}

__global__ __launch_bounds__(256) void k_scan_tile(const int* __restrict__ v, int* __restrict__ tmp,
                                                   int* __restrict__ bsum, int n) {
    __shared__ int s[256];
    int tid = threadIdx.x;
    int i = blockIdx.x * 256 + tid;
    int x = (i < n) ? v[i] : 0;
    s[tid] = x;
    __syncthreads();
    for (int off = 1; off < 256; off <<= 1) {
        int t = (tid >= off) ? s[tid - off] : 0;
        __syncthreads();
        s[tid] += t;
        __syncthreads();
    }
    if (i < n) tmp[i] = s[tid];
    if (tid == 255) bsum[blockIdx.x] = s[255];
}

__global__ __launch_bounds__(1024) void k_scan_bsum(int* bsum, int nb) {
    __shared__ int s[1024];
    int tid = threadIdx.x;
    int v = (tid < nb) ? bsum[tid] : 0;
    s[tid] = v;
    __syncthreads();
    for (int off = 1; off < 1024; off <<= 1) {
        int t = (tid >= off) ? s[tid - off] : 0;
        __syncthreads();
        s[tid] += t;
        __syncthreads();
    }
    if (tid < nb) bsum[tid] = s[tid] - v;  // exclusive
}

__global__ __launch_bounds__(256) void k_exclfin(const int* __restrict__ tmp, const int* __restrict__ bsum,
                                                 const int* __restrict__ counts, int* __restrict__ S, int n) {
    int i = blockIdx.x * 256 + threadIdx.x;
    if (i < n) S[i] = tmp[i] + bsum[i >> 8] - counts[i];
}

__global__ __launch_bounds__(256) void k_bscatter(const int* __restrict__ dst, const int* __restrict__ src,
                                                  const int* __restrict__ S, int* __restrict__ bpacked) {
    __shared__ int cnt[NBKT];
    __shared__ int lst[NBKT];
    __shared__ int cur[NBKT];
    __shared__ int gbase[NBKT];
    __shared__ int sortedv[CHUNK];
    __shared__ int gpos[CHUNK];
    int tid = threadIdx.x, blk = blockIdx.x;
    for (int i = tid; i < NBKT; i += 256) {
        cnt[i] = 0; cur[i] = 0;
        gbase[i] = S[i * NBLK1 + blk];
    }
    __syncthreads();
    int e0 = blk * CHUNK, ee = min(e0 + CHUNK, NE);
    for (int i = e0 + tid; i < ee; i += 256) atomicAdd(&cnt[dst[i] >> 8], 1);
    __syncthreads();
    if (tid < 64) excl_scan_lds(cnt, lst, NBKT, 7);
    __syncthreads();
    for (int i = e0 + tid; i < ee; i += 256) {
        int d = dst[i];
        int b = d >> 8;
        int r = atomicAdd(&cur[b], 1);
        int t = lst[b] + r;
        sortedv[t] = (src[i] << 8) | (d & 255);
        gpos[t] = gbase[b] + r;
    }
    __syncthreads();
    int m = ee - e0;
    for (int t = tid; t < m; t += 256) bpacked[gpos[t]] = sortedv[t];
}

__global__ __launch_bounds__(256) void k_bsort(const int* __restrict__ S, const int* __restrict__ bpacked,
                                               int* __restrict__ srcp, int* __restrict__ rowptr) {
    __shared__ int ed[CAP3];
    __shared__ int cnt[256], lst[256], cur[256];
    int tid = threadIdx.x, b = blockIdx.x;
    int ebeg = S[b * NBLK1];
    int eend = (b + 1 < NBKT) ? S[(b + 1) * NBLK1] : NE;
    int m = min(eend - ebeg, CAP3);
    cnt[tid] = 0; cur[tid] = 0;
    __syncthreads();
    for (int i = tid; i < m; i += 256) {
        int e = bpacked[ebeg + i];
        ed[i] = e;
        atomicAdd(&cnt[e & 255], 1);
    }
    __syncthreads();
    if (tid < 64) excl_scan_lds(cnt, lst, 256, 4);
    __syncthreads();
    int gnode = b * 256 + tid;
    if (gnode < NN) rowptr[gnode] = ebeg + lst[tid];
    if (b == NBKT - 1 && tid == 0) rowptr[NN] = NE;
    for (int i = tid; i < m; i += 256) {
        int e = ed[i];
        int dl = e & 255;
        int r = atomicAdd(&cur[dl], 1);
        srcp[ebeg + lst[dl] + r] = e >> 8;
    }
}

// ---------------- lin0: h0 = relu(x @ W0), [N,128]@[128,16] ----------------
__global__ __launch_bounds__(256) void k_lin0(const float* __restrict__ x, const float* __restrict__ w0,
                                              float* __restrict__ h0, int n) {
    __shared__ float xs[16 * 129];
    __shared__ float ws[128 * 16];
    int tid = threadIdx.x;
    int rowbase = blockIdx.x * 16;
    for (int j = tid; j < 2048; j += 256) ws[j] = w0[j];
    for (int j = tid; j < 2048; j += 256) {
        int r = j >> 7, c = j & 127;
        xs[r * 129 + c] = x[(size_t)rowbase * 128 + j];
    }
    __syncthreads();
    int rloc = tid >> 4, col = tid & 15;
    float acc = 0.f;
#pragma unroll 8
    for (int k = 0; k < 128; ++k) acc = fmaf(xs[rloc * 129 + k], ws[k * 16 + col], acc);
    h0[(size_t)rowbase * 16 + tid] = fmaxf(acc, 0.f);
}

// ---------------- node transforms: [N,K] -> 3x [N,96] ----------------
// Unified xform theory (R4..R7 post-mortems):
//   (a) LDS pipe is 1/CU vs 4 SIMDs; b128 costs ~12 cyc EVEN WHEN BROADCAST
//       (validated: R4's 101 us == LDS-pipe model prediction 94 us)
//       -> must keep <=1 ds_read_b128 per thread per k  (4 nodes, 6 cols: 24 FMA/k).
//   (b) per-k weight loads from global stall at L2 latency; the compiler never
//       software-pipelines them (R7: balanced pipes yet VALUBusy 25%).
//       -> explicit ping-pong REGISTER double-buffer of 4-k weight chunks:
//          chunk c+1's 12 dwordx2 issue ~200 cyc (96 FMAs) ahead of first use.
// Live regs ~90 (24 acc + 48 wbuf + xs + addr); launch_bounds(384,2) caps at 256.
#define XF_FMA_CHUNK(BL, BR, BF)                                             \
    _Pragma("unroll")                                                        \
    for (int kk = 0; kk < 4; ++kk) {                                         \
        v4f xs = *(const v4f*)(xT + (size_t)(kb + kk) * 36 + ty * 4);        \
        float2 wl2 = BL[kk], wr2 = BR[kk], wf2 = BF[kk];                     \
        _Pragma("unroll")                                                    \
        for (int j = 0; j < 4; ++j) {                                        \
            acc[0][j] = fmaf(xs[j], wl2.x, acc[0][j]);                       \
            acc[1][j] = fmaf(xs[j], wl2.y, acc[1][j]);                       \
            acc[2][j] = fmaf(xs[j], wr2.x, acc[2][j]);                       \
            acc[3][j] = fmaf(xs[j], wr2.y, acc[3][j]);                       \
            acc[4][j] = fmaf(xs[j], wf2.x, acc[4][j]);                       \
            acc[5][j] = fmaf(xs[j], wf2.y, acc[5][j]);                       \
        }                                                                    \
    }

#define XF_LOAD_CHUNK(BL, BR, BF, KBASE)                                     \
    _Pragma("unroll")                                                        \
    for (int kk = 0; kk < 4; ++kk) {                                         \
        int ks = (KBASE) + kk;                                               \
        BL[kk] = *(const float2*)(pl + (size_t)ks * 96);                     \
        BR[kk] = *(const float2*)(pr + (size_t)ks * 96);                     \
        BF[kk] = *(const float2*)(pf + (size_t)ks * 96);                     \
    }

template<int K>
__global__ __launch_bounds__(384, 2) void k_xform(const float* __restrict__ hin,
                                                  const float* __restrict__ Wl, const float* __restrict__ bl,
                                                  const float* __restrict__ Wr, const float* __restrict__ br,
                                                  const float* __restrict__ Wf, const float* __restrict__ bf,
                                                  float* __restrict__ HL, float* __restrict__ HR,
                                                  float* __restrict__ SK) {
    __shared__ float xT[K * 36];                 // [k][node], 32 nodes padded to 36
    int tx = threadIdx.x;                        // 0..47: col pair (2tx, 2tx+1)
    int ty = threadIdx.y;                        // 0..7: node group (4 nodes)
    int tid = ty * 48 + tx;
    int base = blockIdx.x * 32;
    constexpr int NF4 = 32 * K / 4;
    for (int j = tid; j < NF4; j += 384) {
        int node = j / (K / 4);
        int c4 = j - node * (K / 4);
        float4 v = *(const float4*)(hin + (size_t)base * K + (size_t)j * 4);
        xT[(4 * c4 + 0) * 36 + node] = v.x;
        xT[(4 * c4 + 1) * 36 + node] = v.y;
        xT[(4 * c4 + 2) * 36 + node] = v.z;
        xT[(4 * c4 + 3) * 36 + node] = v.w;
    }
    __syncthreads();
    int col = 2 * tx;
    const float* pl = Wl + col;
    const float* pr = Wr + col;
    const float* pf = Wf + col;
    float acc[6][4];
#pragma unroll
    for (int m = 0; m < 6; ++m)
#pragma unroll
        for (int j = 0; j < 4; ++j) acc[m][j] = 0.f;

    constexpr int NCH = K / 4;                   // 24 for K=96, 4 for K=16
    float2 al[4], ar[4], af[4];                  // buffer A
    float2 nl[4], nr[4], nf[4];                  // buffer B
    XF_LOAD_CHUNK(al, ar, af, 0)
    for (int c = 0; c < NCH; c += 2) {
        int kb = c * 4;
        {   // prefetch chunk c+1 into B (clamped if last)
            int kpre = (c + 1 < NCH) ? kb + 4 : kb;
            XF_LOAD_CHUNK(nl, nr, nf, kpre)
        }
        XF_FMA_CHUNK(al, ar, af)
        kb += 4;
        {   // prefetch chunk c+2 into A (clamped)
            int kpre = (c + 2 < NCH) ? kb + 4 : kb - 4;
            XF_LOAD_CHUNK(al, ar, af, kpre)
        }
        XF_FMA_CHUNK(nl, nr, nf)
    }

    float2 blv = *(const float2*)(bl + col);
    float2 brv = *(const float2*)(br + col);
    float2 bfv = *(const float2*)(bf + col);
#pragma unroll
    for (int j = 0; j < 4; ++j) {
        size_t o = (size_t)(base + ty * 4 + j) * 96 + col;
        *(float2*)(HL + o) = make_float2(acc[0][j] + blv.x, acc[1][j] + blv.y);
        *(float2*)(HR + o) = make_float2(acc[2][j] + brv.x, acc[3][j] + brv.y);
        *(float2*)(SK + o) = make_float2(acc[4][j] + bfv.x, acc[5][j] + bfv.y);
    }
}

// ---------------- GATv2 aggregation (R4 known-good: 2 gather chains) ----------------
__global__ __launch_bounds__(256) void k_agg(const int* __restrict__ rowptr, const int* __restrict__ srcp,
                                             const float* __restrict__ HL, const float* __restrict__ HR,
                                             const float* __restrict__ att, const float* __restrict__ bias,
                                             const float* __restrict__ SK, float* __restrict__ out,
                                             int n, int do_relu) {
    int node = (blockIdx.x * 256 + threadIdx.x) >> 6;
    int lane = threadIdx.x & 63;
    if (node >= n) return;
    int hl5 = lane & 31;
    int half = lane >> 5;
    bool active = hl5 < 24;
    int c = active ? 4 * hl5 : 92;
    float4 hr = *(const float4*)(HR + (size_t)node * 96 + c);
    float4 at = *(const float4*)(att + c);
    int beg = rowptr[node], end = rowptr[node + 1];
    float4 acc0 = {0.f,0.f,0.f,0.f}, acc1 = {0.f,0.f,0.f,0.f};
    float l0 = 0.f, l1 = 0.f;

#define EDGE(IDX, ACC, LACC) {                                           \
        int sj = __shfl(ss, (IDX), 64);                                  \
        float4 a = *(const float4*)(HL + 96u * (unsigned)sj + c);        \
        float v0 = hr.x + a.x, v1 = hr.y + a.y;                          \
        float v2 = hr.z + a.z, v3 = hr.w + a.w;                          \
        v0 = fmaxf(v0, 0.2f * v0); v1 = fmaxf(v1, 0.2f * v1);            \
        v2 = fmaxf(v2, 0.2f * v2); v3 = fmaxf(v3, 0.2f * v3);            \
        float tt = fmaf(v3, at.w, fmaf(v2, at.z, fmaf(v1, at.y, v0 * at.x))); \
        tt += __shfl_xor(tt, 1); tt += __shfl_xor(tt, 2);                \
        tt += __shfl_xor(tt, 4);                                         \
        float p = ((IDX) < cnt) ? __expf(tt) : 0.f;                      \
        LACC += p;                                                       \
        ACC.x = fmaf(p, a.x, ACC.x); ACC.y = fmaf(p, a.y, ACC.y);        \
        ACC.z = fmaf(p, a.z, ACC.z); ACC.w = fmaf(p, a.w, ACC.w);        \
    }

    for (int cb = beg; cb < end; cb += 64) {
        int cnt = min(64, end - cb);
        int my = cb + lane;
        int ss = (my < end) ? srcp[my] : 0;
        int npair = (cnt + 1) >> 1;
        int idx = half;
        int j = 0;
        for (; j + 2 <= npair; j += 2) {
            EDGE(idx, acc0, l0)
            EDGE(idx + 2, acc1, l1)
            idx += 4;
        }
        if (j < npair) EDGE(idx, acc0, l0)
    }
#undef EDGE

    acc0.x += acc1.x; acc0.y += acc1.y; acc0.z += acc1.z; acc0.w += acc1.w;
    float l = l0 + l1;
    int partner = hl5 + 32;
    acc0.x += __shfl(acc0.x, partner, 64);
    acc0.y += __shfl(acc0.y, partner, 64);
    acc0.z += __shfl(acc0.z, partner, 64);
    acc0.w += __shfl(acc0.w, partner, 64);
    l      += __shfl(l, partner, 64);

    if (half == 0 && active) {
        float inv = 1.0f / (l + 1e-16f);
        size_t o = (size_t)node * 96 + c;
        float4 sk = *(const float4*)(SK + o);
        float4 bs = *(const float4*)(bias + c);
        float4 ov;
        ov.x = fmaf(acc0.x, inv, bs.x + sk.x);
        ov.y = fmaf(acc0.y, inv, bs.y + sk.y);
        ov.z = fmaf(acc0.z, inv, bs.z + sk.z);
        ov.w = fmaf(acc0.w, inv, bs.w + sk.w);
        if (do_relu) {
            ov.x = fmaxf(ov.x, 0.f); ov.y = fmaxf(ov.y, 0.f);
            ov.z = fmaxf(ov.z, 0.f); ov.w = fmaxf(ov.w, 0.f);
        }
        *(float4*)(out + o) = ov;
    }
}

extern "C" void kernel_launch(void* const* d_in, const int* in_sizes, int n_in,
                              void* d_out, int out_size, void* d_ws, size_t ws_size,
                              hipStream_t stream) {
    const float* x     = (const float*)d_in[0];
    const int*   ei    = (const int*)d_in[1];    // [2,E]: src = ei[0:E], dst = ei[E:2E]
    const float* W0    = (const float*)d_in[2];
    const float* Wl1   = (const float*)d_in[3];
    const float* bl1   = (const float*)d_in[4];
    const float* Wr1   = (const float*)d_in[5];
    const float* br1   = (const float*)d_in[6];
    const float* att1  = (const float*)d_in[7];
    const float* b1    = (const float*)d_in[8];
    const float* Wf    = (const float*)d_in[9];
    const float* bf    = (const float*)d_in[10];
    const float* Wl2   = (const float*)d_in[11];
    const float* bl2   = (const float*)d_in[12];
    const float* Wr2   = (const float*)d_in[13];
    const float* br2   = (const float*)d_in[14];
    const float* att2  = (const float*)d_in[15];
    const float* b2    = (const float*)d_in[16];
    const float* Wlast = (const float*)d_in[17];
    const float* blast = (const float*)d_in[18];

    const int* src = ei;
    const int* dst = ei + NE;

    size_t off = 0;
    auto carve = [&](size_t bytes) {
        void* p = (char*)d_ws + off;
        off += (bytes + 255) & ~(size_t)255;
        return p;
    };
    float* HL  = (float*)carve((size_t)NN * 96 * 4);
    float* HR  = (float*)carve((size_t)NN * 96 * 4);
    float* SK  = (float*)carve((size_t)NN * 96 * 4);
    float* H   = (float*)carve((size_t)NN * 96 * 4);   // h1; bpacked aliases this
    float* h0  = (float*)carve((size_t)NN * 16 * 4);
    int* rowptr  = (int*)carve((size_t)(NN + 1) * 4);
    int* srcp    = (int*)carve((size_t)NE * 4);
    int* counts  = (int*)carve((size_t)SCAN_N * 4);
    int* scantmp = (int*)carve((size_t)SCAN_N * 4);
    int* S       = (int*)carve((size_t)SCAN_N * 4);
    int* bsum    = (int*)carve(1024 * 4);
    int* bpacked = (int*)H;   // alias: dead before k_agg writes H
    (void)ws_size; (void)n_in; (void)in_sizes; (void)out_size;

    const int SCAN_TILES = (SCAN_N + 255) / 256;   // 598
    const int XF_BLOCKS = NN / 32;                 // 3125, exact

    // CSR build (atomic-free at global scope)
    k_bcount<<<NBLK1, 256, 0, stream>>>(dst, counts);
    k_scan_tile<<<SCAN_TILES, 256, 0, stream>>>(counts, scantmp, bsum, SCAN_N);
    k_scan_bsum<<<1, 1024, 0, stream>>>(bsum, SCAN_TILES);
    k_exclfin<<<SCAN_TILES, 256, 0, stream>>>(scantmp, bsum, counts, S, SCAN_N);
    k_bscatter<<<NBLK1, 256, 0, stream>>>(dst, src, S, bpacked);
    k_bsort<<<NBKT, 256, 0, stream>>>(S, bpacked, srcp, rowptr);

    // dense pipeline, layer 1
    k_lin0<<<NN / 16, 256, 0, stream>>>(x, W0, h0, NN);
    k_xform<16><<<XF_BLOCKS, dim3(48, 8), 0, stream>>>(h0, Wl1, bl1, Wr1, br1, Wf, bf, HL, HR, SK);
    k_agg<<<(NN + 3) / 4, 256, 0, stream>>>(rowptr, srcp, HL, HR, att1, b1, SK, H, NN, 1);

    // layer 2
    k_xform<96><<<XF_BLOCKS, dim3(48, 8), 0, stream>>>(H, Wl2, bl2, Wr2, br2, Wlast, blast, HL, HR, SK);
    k_agg<<<(NN + 3) / 4, 256, 0, stream>>>(rowptr, srcp, HL, HR, att2, b2, SK, (float*)d_out, NN, 0);
}

// Round 9
// 578.226 us; speedup vs baseline: 1.0995x; 1.0995x over previous
//
#include <hip/hip_runtime.h>
#include <cstdint>
#include <cfloat>

#define NN 100000
#define NE 1600000
#define NBKT 391          // buckets of 256 dst nodes: (NN+255)/256
#define CHUNK 4096
#define NBLK1 391         // ceil(NE/CHUNK)
#define SCAN_N (NBKT * NBLK1)   // 152881
#define CAP3 5120         // max edges per bucket (mean 4096, sigma 64 -> 16 sigma)

typedef float v4f __attribute__((ext_vector_type(4)));

// wave-0 exclusive scan of cnt[0..nelem) -> lst; caller guards threadIdx.x < 64
__device__ __forceinline__ void excl_scan_lds(const int* cnt, int* lst, int nelem, int per_lane) {
    int lane = threadIdx.x & 63;
    int base = lane * per_lane;
    int run = 0;
    int loc[8];
    for (int j = 0; j < per_lane; ++j) {
        int idx = base + j;
        loc[j] = run;
        if (idx < nelem) run += cnt[idx];
    }
    int tot = run;
    for (int off = 1; off < 64; off <<= 1) {
        int t = __shfl_up(tot, off);
        if (lane >= off) tot += t;
    }
    int pre = tot - run;
    for (int j = 0; j < per_lane; ++j) {
        int idx = base + j;
        if (idx < nelem) lst[idx] = pre + loc[j];
    }
}

// ---------------- CSR build: atomic-free bucket sort (R4, unchanged) ----------------
__global__ __launch_bounds__(256) void k_bcount(const int* __restrict__ dst, int* __restrict__ counts) {
    __shared__ int h[NBKT];
    int tid = threadIdx.x, blk = blockIdx.x;
    for (int i = tid; i < NBKT; i += 256) h[i] = 0;
    __syncthreads();
    int e0 = blk * CHUNK, ee = min(e0 + CHUNK, NE);
    for (int i = e0 + tid; i < ee; i += 256) atomicAdd(&h[dst[i] >> 8], 1);
    __syncthreads();
    for (int i = tid; i < NBKT; i += 256) counts[i * NBLK1 + blk] = h[i];
}

__global__ __launch_bounds__(256) void k_scan_tile(const int* __restrict__ v, int* __restrict__ tmp,
                                                   int* __restrict__ bsum, int n) {
    __shared__ int s[256];
    int tid = threadIdx.x;
    int i = blockIdx.x * 256 + tid;
    int x = (i < n) ? v[i] : 0;
    s[tid] = x;
    __syncthreads();
    for (int off = 1; off < 256; off <<= 1) {
        int t = (tid >= off) ? s[tid - off] : 0;
        __syncthreads();
        s[tid] += t;
        __syncthreads();
    }
    if (i < n) tmp[i] = s[tid];
    if (tid == 255) bsum[blockIdx.x] = s[255];
}

__global__ __launch_bounds__(1024) void k_scan_bsum(int* bsum, int nb) {
    __shared__ int s[1024];
    int tid = threadIdx.x;
    int v = (tid < nb) ? bsum[tid] : 0;
    s[tid] = v;
    __syncthreads();
    for (int off = 1; off < 1024; off <<= 1) {
        int t = (tid >= off) ? s[tid - off] : 0;
        __syncthreads();
        s[tid] += t;
        __syncthreads();
    }
    if (tid < nb) bsum[tid] = s[tid] - v;  // exclusive
}

__global__ __launch_bounds__(256) void k_exclfin(const int* __restrict__ tmp, const int* __restrict__ bsum,
                                                 const int* __restrict__ counts, int* __restrict__ S, int n) {
    int i = blockIdx.x * 256 + threadIdx.x;
    if (i < n) S[i] = tmp[i] + bsum[i >> 8] - counts[i];
}

__global__ __launch_bounds__(256) void k_bscatter(const int* __restrict__ dst, const int* __restrict__ src,
                                                  const int* __restrict__ S, int* __restrict__ bpacked) {
    __shared__ int cnt[NBKT];
    __shared__ int lst[NBKT];
    __shared__ int cur[NBKT];
    __shared__ int gbase[NBKT];
    __shared__ int sortedv[CHUNK];
    __shared__ int gpos[CHUNK];
    int tid = threadIdx.x, blk = blockIdx.x;
    for (int i = tid; i < NBKT; i += 256) {
        cnt[i] = 0; cur[i] = 0;
        gbase[i] = S[i * NBLK1 + blk];
    }
    __syncthreads();
    int e0 = blk * CHUNK, ee = min(e0 + CHUNK, NE);
    for (int i = e0 + tid; i < ee; i += 256) atomicAdd(&cnt[dst[i] >> 8], 1);
    __syncthreads();
    if (tid < 64) excl_scan_lds(cnt, lst, NBKT, 7);
    __syncthreads();
    for (int i = e0 + tid; i < ee; i += 256) {
        int d = dst[i];
        int b = d >> 8;
        int r = atomicAdd(&cur[b], 1);
        int t = lst[b] + r;
        sortedv[t] = (src[i] << 8) | (d & 255);
        gpos[t] = gbase[b] + r;
    }
    __syncthreads();
    int m = ee - e0;
    for (int t = tid; t < m; t += 256) bpacked[gpos[t]] = sortedv[t];
}

__global__ __launch_bounds__(256) void k_bsort(const int* __restrict__ S, const int* __restrict__ bpacked,
                                               int* __restrict__ srcp, int* __restrict__ rowptr) {
    __shared__ int ed[CAP3];
    __shared__ int cnt[256], lst[256], cur[256];
    int tid = threadIdx.x, b = blockIdx.x;
    int ebeg = S[b * NBLK1];
    int eend = (b + 1 < NBKT) ? S[(b + 1) * NBLK1] : NE;
    int m = min(eend - ebeg, CAP3);
    cnt[tid] = 0; cur[tid] = 0;
    __syncthreads();
    for (int i = tid; i < m; i += 256) {
        int e = bpacked[ebeg + i];
        ed[i] = e;
        atomicAdd(&cnt[e & 255], 1);
    }
    __syncthreads();
    if (tid < 64) excl_scan_lds(cnt, lst, 256, 4);
    __syncthreads();
    int gnode = b * 256 + tid;
    if (gnode < NN) rowptr[gnode] = ebeg + lst[tid];
    if (b == NBKT - 1 && tid == 0) rowptr[NN] = NE;
    for (int i = tid; i < m; i += 256) {
        int e = ed[i];
        int dl = e & 255;
        int r = atomicAdd(&cur[dl], 1);
        srcp[ebeg + lst[dl] + r] = e >> 8;
    }
}

// ---------------- lin0: h0 = relu(x @ W0), [N,128]@[128,16] ----------------
__global__ __launch_bounds__(256) void k_lin0(const float* __restrict__ x, const float* __restrict__ w0,
                                              float* __restrict__ h0, int n) {
    __shared__ float xs[16 * 129];
    __shared__ float ws[128 * 16];
    int tid = threadIdx.x;
    int rowbase = blockIdx.x * 16;
    for (int j = tid; j < 2048; j += 256) ws[j] = w0[j];
    for (int j = tid; j < 2048; j += 256) {
        int r = j >> 7, c = j & 127;
        xs[r * 129 + c] = x[(size_t)rowbase * 128 + j];
    }
    __syncthreads();
    int rloc = tid >> 4, col = tid & 15;
    float acc = 0.f;
#pragma unroll 8
    for (int k = 0; k < 128; ++k) acc = fmaf(xs[rloc * 129 + k], ws[k * 16 + col], acc);
    h0[(size_t)rowbase * 16 + tid] = fmaxf(acc, 0.f);
}

// ---------------- node transforms: [N,K] -> 3x [N,96] ----------------
// R4..R8 empirical law: xform time ~ total weight-load wave-instructions (each exposes
// ~90 cyc; compiler never hides it). Levers: (1) weight reuse = nodes/block -> 128 here
// (782 blocks: 2x fewer weight fetches than R4's 64-node tiles, 4x fewer than R7/R8);
// (2) wider loads: 4 adjacent cols x 3 mats = 3 dwordx4 per k (vs R4's 3 dword).
// Thread = 4 cols x 3 mats x 8 nodes: per k = 2 ds_read_b128 (24 LDS cyc) + 3 dwordx4
// + 96 FMA (192 VALU cyc) -> VALU:LDS 8:1 (R4 was 1:1). 96 accs live in AGPRs (gfx950
// unified file; R4's VGPR_Count=44 with 48 accs proved AGPR absorption is free).
// LDS 96*132*4 = 50.7 KB -> 3 blocks/CU.
template<int K>
__global__ __launch_bounds__(384) void k_xform(const float* __restrict__ hin,
                                               const float* __restrict__ Wl, const float* __restrict__ bl,
                                               const float* __restrict__ Wr, const float* __restrict__ br,
                                               const float* __restrict__ Wf, const float* __restrict__ bf,
                                               float* __restrict__ HL, float* __restrict__ HR,
                                               float* __restrict__ SK, int n) {
    __shared__ float xT[K * 132];                // [k][node], 128 nodes padded to 132
    int tx = threadIdx.x;                        // 0..23: col quad (4*tx)
    int ty = threadIdx.y;                        // 0..15: node group (8 nodes)
    int tid = ty * 24 + tx;
    int base = blockIdx.x * 128;
    constexpr int NF4 = 128 * K / 4;             // float4s to stage (3072 for K=96)
    for (int j = tid; j < NF4; j += 384) {
        int node = j / (K / 4);
        int c4 = j - node * (K / 4);
        float4 v = {0.f, 0.f, 0.f, 0.f};
        if (base + node < n) v = *(const float4*)(hin + (size_t)(base + node) * K + 4 * c4);
        xT[(4 * c4 + 0) * 132 + node] = v.x;
        xT[(4 * c4 + 1) * 132 + node] = v.y;
        xT[(4 * c4 + 2) * 132 + node] = v.z;
        xT[(4 * c4 + 3) * 132 + node] = v.w;
    }
    __syncthreads();
    int col = 4 * tx;
    float4 al[8], ar[8], af[8];                  // [node][4 cols], 96 floats -> AGPRs
#pragma unroll
    for (int j = 0; j < 8; ++j) {
        al[j] = make_float4(0.f, 0.f, 0.f, 0.f);
        ar[j] = make_float4(0.f, 0.f, 0.f, 0.f);
        af[j] = make_float4(0.f, 0.f, 0.f, 0.f);
    }
#pragma unroll 2
    for (int k = 0; k < K; ++k) {
        float4 wl = *(const float4*)(Wl + k * 96 + col);
        float4 wr = *(const float4*)(Wr + k * 96 + col);
        float4 wf = *(const float4*)(Wf + k * 96 + col);
        const float* row = xT + (size_t)k * 132 + ty * 8;
        v4f x0 = *(const v4f*)(row);
        v4f x1 = *(const v4f*)(row + 4);
#pragma unroll
        for (int j = 0; j < 4; ++j) {
            float xv = x0[j];
            al[j].x = fmaf(xv, wl.x, al[j].x); al[j].y = fmaf(xv, wl.y, al[j].y);
            al[j].z = fmaf(xv, wl.z, al[j].z); al[j].w = fmaf(xv, wl.w, al[j].w);
            ar[j].x = fmaf(xv, wr.x, ar[j].x); ar[j].y = fmaf(xv, wr.y, ar[j].y);
            ar[j].z = fmaf(xv, wr.z, ar[j].z); ar[j].w = fmaf(xv, wr.w, ar[j].w);
            af[j].x = fmaf(xv, wf.x, af[j].x); af[j].y = fmaf(xv, wf.y, af[j].y);
            af[j].z = fmaf(xv, wf.z, af[j].z); af[j].w = fmaf(xv, wf.w, af[j].w);
        }
#pragma unroll
        for (int j = 0; j < 4; ++j) {
            float xv = x1[j];
            int q = 4 + j;
            al[q].x = fmaf(xv, wl.x, al[q].x); al[q].y = fmaf(xv, wl.y, al[q].y);
            al[q].z = fmaf(xv, wl.z, al[q].z); al[q].w = fmaf(xv, wl.w, al[q].w);
            ar[q].x = fmaf(xv, wr.x, ar[q].x); ar[q].y = fmaf(xv, wr.y, ar[q].y);
            ar[q].z = fmaf(xv, wr.z, ar[q].z); ar[q].w = fmaf(xv, wr.w, ar[q].w);
            af[q].x = fmaf(xv, wf.x, af[q].x); af[q].y = fmaf(xv, wf.y, af[q].y);
            af[q].z = fmaf(xv, wf.z, af[q].z); af[q].w = fmaf(xv, wf.w, af[q].w);
        }
    }
    float4 blv = *(const float4*)(bl + col);
    float4 brv = *(const float4*)(br + col);
    float4 bfv = *(const float4*)(bf + col);
#pragma unroll
    for (int j = 0; j < 8; ++j) {
        int node = base + ty * 8 + j;
        if (node < n) {
            size_t o = (size_t)node * 96 + col;
            *(float4*)(HL + o) = make_float4(al[j].x + blv.x, al[j].y + blv.y,
                                             al[j].z + blv.z, al[j].w + blv.w);
            *(float4*)(HR + o) = make_float4(ar[j].x + brv.x, ar[j].y + brv.y,
                                             ar[j].z + brv.z, ar[j].w + brv.w);
            *(float4*)(SK + o) = make_float4(af[j].x + bfv.x, af[j].y + bfv.y,
                                             af[j].z + bfv.z, af[j].w + bfv.w);
        }
    }
}

// ---------------- GATv2 aggregation (R4 known-good: 2 gather chains) ----------------
__global__ __launch_bounds__(256) void k_agg(const int* __restrict__ rowptr, const int* __restrict__ srcp,
                                             const float* __restrict__ HL, const float* __restrict__ HR,
                                             const float* __restrict__ att, const float* __restrict__ bias,
                                             const float* __restrict__ SK, float* __restrict__ out,
                                             int n, int do_relu) {
    int node = (blockIdx.x * 256 + threadIdx.x) >> 6;
    int lane = threadIdx.x & 63;
    if (node >= n) return;
    int hl5 = lane & 31;
    int half = lane >> 5;
    bool active = hl5 < 24;
    int c = active ? 4 * hl5 : 92;
    float4 hr = *(const float4*)(HR + (size_t)node * 96 + c);
    float4 at = *(const float4*)(att + c);
    int beg = rowptr[node], end = rowptr[node + 1];
    float4 acc0 = {0.f,0.f,0.f,0.f}, acc1 = {0.f,0.f,0.f,0.f};
    float l0 = 0.f, l1 = 0.f;

#define EDGE(IDX, ACC, LACC) {                                           \
        int sj = __shfl(ss, (IDX), 64);                                  \
        float4 a = *(const float4*)(HL + 96u * (unsigned)sj + c);        \
        float v0 = hr.x + a.x, v1 = hr.y + a.y;                          \
        float v2 = hr.z + a.z, v3 = hr.w + a.w;                          \
        v0 = fmaxf(v0, 0.2f * v0); v1 = fmaxf(v1, 0.2f * v1);            \
        v2 = fmaxf(v2, 0.2f * v2); v3 = fmaxf(v3, 0.2f * v3);            \
        float tt = fmaf(v3, at.w, fmaf(v2, at.z, fmaf(v1, at.y, v0 * at.x))); \
        tt += __shfl_xor(tt, 1); tt += __shfl_xor(tt, 2);                \
        tt += __shfl_xor(tt, 4);                                         \
        float p = ((IDX) < cnt) ? __expf(tt) : 0.f;                      \
        LACC += p;                                                       \
        ACC.x = fmaf(p, a.x, ACC.x); ACC.y = fmaf(p, a.y, ACC.y);        \
        ACC.z = fmaf(p, a.z, ACC.z); ACC.w = fmaf(p, a.w, ACC.w);        \
    }

    for (int cb = beg; cb < end; cb += 64) {
        int cnt = min(64, end - cb);
        int my = cb + lane;
        int ss = (my < end) ? srcp[my] : 0;
        int npair = (cnt + 1) >> 1;
        int idx = half;
        int j = 0;
        for (; j + 2 <= npair; j += 2) {
            EDGE(idx, acc0, l0)
            EDGE(idx + 2, acc1, l1)
            idx += 4;
        }
        if (j < npair) EDGE(idx, acc0, l0)
    }
#undef EDGE

    acc0.x += acc1.x; acc0.y += acc1.y; acc0.z += acc1.z; acc0.w += acc1.w;
    float l = l0 + l1;
    int partner = hl5 + 32;
    acc0.x += __shfl(acc0.x, partner, 64);
    acc0.y += __shfl(acc0.y, partner, 64);
    acc0.z += __shfl(acc0.z, partner, 64);
    acc0.w += __shfl(acc0.w, partner, 64);
    l      += __shfl(l, partner, 64);

    if (half == 0 && active) {
        float inv = 1.0f / (l + 1e-16f);
        size_t o = (size_t)node * 96 + c;
        float4 sk = *(const float4*)(SK + o);
        float4 bs = *(const float4*)(bias + c);
        float4 ov;
        ov.x = fmaf(acc0.x, inv, bs.x + sk.x);
        ov.y = fmaf(acc0.y, inv, bs.y + sk.y);
        ov.z = fmaf(acc0.z, inv, bs.z + sk.z);
        ov.w = fmaf(acc0.w, inv, bs.w + sk.w);
        if (do_relu) {
            ov.x = fmaxf(ov.x, 0.f); ov.y = fmaxf(ov.y, 0.f);
            ov.z = fmaxf(ov.z, 0.f); ov.w = fmaxf(ov.w, 0.f);
        }
        *(float4*)(out + o) = ov;
    }
}

extern "C" void kernel_launch(void* const* d_in, const int* in_sizes, int n_in,
                              void* d_out, int out_size, void* d_ws, size_t ws_size,
                              hipStream_t stream) {
    const float* x     = (const float*)d_in[0];
    const int*   ei    = (const int*)d_in[1];    // [2,E]: src = ei[0:E], dst = ei[E:2E]
    const float* W0    = (const float*)d_in[2];
    const float* Wl1   = (const float*)d_in[3];
    const float* bl1   = (const float*)d_in[4];
    const float* Wr1   = (const float*)d_in[5];
    const float* br1   = (const float*)d_in[6];
    const float* att1  = (const float*)d_in[7];
    const float* b1    = (const float*)d_in[8];
    const float* Wf    = (const float*)d_in[9];
    const float* bf    = (const float*)d_in[10];
    const float* Wl2   = (const float*)d_in[11];
    const float* bl2   = (const float*)d_in[12];
    const float* Wr2   = (const float*)d_in[13];
    const float* br2   = (const float*)d_in[14];
    const float* att2  = (const float*)d_in[15];
    const float* b2    = (const float*)d_in[16];
    const float* Wlast = (const float*)d_in[17];
    const float* blast = (const float*)d_in[18];

    const int* src = ei;
    const int* dst = ei + NE;

    size_t off = 0;
    auto carve = [&](size_t bytes) {
        void* p = (char*)d_ws + off;
        off += (bytes + 255) & ~(size_t)255;
        return p;
    };
    float* HL  = (float*)carve((size_t)NN * 96 * 4);
    float* HR  = (float*)carve((size_t)NN * 96 * 4);
    float* SK  = (float*)carve((size_t)NN * 96 * 4);
    float* H   = (float*)carve((size_t)NN * 96 * 4);   // h1; bpacked aliases this
    float* h0  = (float*)carve((size_t)NN * 16 * 4);
    int* rowptr  = (int*)carve((size_t)(NN + 1) * 4);
    int* srcp    = (int*)carve((size_t)NE * 4);
    int* counts  = (int*)carve((size_t)SCAN_N * 4);
    int* scantmp = (int*)carve((size_t)SCAN_N * 4);
    int* S       = (int*)carve((size_t)SCAN_N * 4);
    int* bsum    = (int*)carve(1024 * 4);
    int* bpacked = (int*)H;   // alias: dead before k_agg writes H
    (void)ws_size; (void)n_in; (void)in_sizes; (void)out_size;

    const int SCAN_TILES = (SCAN_N + 255) / 256;   // 598
    const int XF_BLOCKS = (NN + 127) / 128;        // 782

    // CSR build (atomic-free at global scope)
    k_bcount<<<NBLK1, 256, 0, stream>>>(dst, counts);
    k_scan_tile<<<SCAN_TILES, 256, 0, stream>>>(counts, scantmp, bsum, SCAN_N);
    k_scan_bsum<<<1, 1024, 0, stream>>>(bsum, SCAN_TILES);
    k_exclfin<<<SCAN_TILES, 256, 0, stream>>>(scantmp, bsum, counts, S, SCAN_N);
    k_bscatter<<<NBLK1, 256, 0, stream>>>(dst, src, S, bpacked);
    k_bsort<<<NBKT, 256, 0, stream>>>(S, bpacked, srcp, rowptr);

    // dense pipeline, layer 1
    k_lin0<<<NN / 16, 256, 0, stream>>>(x, W0, h0, NN);
    k_xform<16><<<XF_BLOCKS, dim3(24, 16), 0, stream>>>(h0, Wl1, bl1, Wr1, br1, Wf, bf, HL, HR, SK, NN);
    k_agg<<<(NN + 3) / 4, 256, 0, stream>>>(rowptr, srcp, HL, HR, att1, b1, SK, H, NN, 1);

    // layer 2
    k_xform<96><<<XF_BLOCKS, dim3(24, 16), 0, stream>>>(H, Wl2, bl2, Wr2, br2, Wlast, blast, HL, HR, SK, NN);
    k_agg<<<(NN + 3) / 4, 256, 0, stream>>>(rowptr, srcp, HL, HR, att2, b2, SK, (float*)d_out, NN, 0);
}